// Round 10
// baseline (382.126 us; speedup 1.0000x reference)
//
#include <hip/hip_runtime.h>
#include <math.h>

#define IN_F 128
#define F1 256   // H1*C1
#define H1 2
#define F2 64
#define NEG 0.2f

// ---------------- tiled fp32 GEMM: TM x TN tile, RM x RN per thread ----------
// Register-prefetch pipeline: chunk c+1 is global-loaded into VGPRs while
// chunk c computes from LDS (overlaps vmem latency with FMA; the old
// load->drain->barrier->compute structure exposed it serially).
// Split-column mapping (RN==8): cols {tx*4..+3} u {TN/2+tx*4..+3} -> Ws reads
// at 16B stride (2-way multicast, conflict-free; verified round 9).
template<int KTOT, int TM, int TN, int RM, int RN, int LDA, int LDW, int LDC,
         bool RELU, bool ATT_EP, bool HEADOFF>
__global__ __launch_bounds__(256) void gemm_tiled(
    const float* __restrict__ A, const float* __restrict__ bias,
    const float* __restrict__ W, float* __restrict__ C,
    const float* __restrict__ att_s, const float* __restrict__ att_d,
    float* __restrict__ a_src, float* __restrict__ a_dst, int M)
{
    constexpr int NX = TN / RN;
    constexpr int NY = 256 / NX;
    static_assert(NY * RM == TM, "tile mismatch");
    static_assert(RN == 8, "split-col mapping assumes RN==8");
    constexpr int NCHUNK = KTOT / 32;
    __shared__ float As[32][TM];
    __shared__ float Ws[32][TN];
    int t = threadIdx.x;
    int tx = t % NX, ty = t / NX;
    int m0 = blockIdx.x * TM;
    int n0 = blockIdx.y * TN;
    long aoff = HEADOFF ? (long)blockIdx.y * KTOT : 0;
    float acc[RM][RN];
    #pragma unroll
    for (int i = 0; i < RM; ++i)
        #pragma unroll
        for (int j = 0; j < RN; ++j) acc[i][j] = 0.f;

    constexpr int PARTS = 256 / TM;     // threads per A row
    constexpr int F4PT = 8 / PARTS;     // A float4 per thread per chunk
    int ar = t % TM, apart = t / TM;
    int arow = m0 + ar; if (arow >= M) arow = M - 1;
    constexpr int WTPK = TN / 4;        // threads per W k-row
    constexpr int WKP = 256 / WTPK;     // k-rows per pass
    constexpr int WF4 = 32 / WKP;       // W float4 per thread per chunk
    int wk0 = t / WTPK, wc = t % WTPK;

    const float* abase = A + (long)arow * LDA + aoff + apart * (F4PT * 4);
    float4 areg[F4PT], wreg[WF4];

    // prefetch chunk 0
    #pragma unroll
    for (int p = 0; p < F4PT; ++p)
        areg[p] = *(const float4*)(abase + p * 4);
    #pragma unroll
    for (int p = 0; p < WF4; ++p)
        wreg[p] = *(const float4*)&W[(long)(wk0 + p * WKP) * LDW + n0 + wc * 4];

    for (int c = 0; c < NCHUNK; ++c) {
        // regs (chunk c) -> LDS
        #pragma unroll
        for (int p = 0; p < F4PT; ++p) {
            int kk = apart * (F4PT * 4) + p * 4;
            float4 v = areg[p];
            if (RELU) {
                float4 bb = *(const float4*)&bias[c * 32 + kk];
                v.x = fmaxf(v.x + bb.x, 0.f);
                v.y = fmaxf(v.y + bb.y, 0.f);
                v.z = fmaxf(v.z + bb.z, 0.f);
                v.w = fmaxf(v.w + bb.w, 0.f);
            }
            As[kk + 0][ar] = v.x;
            As[kk + 1][ar] = v.y;
            As[kk + 2][ar] = v.z;
            As[kk + 3][ar] = v.w;
        }
        #pragma unroll
        for (int p = 0; p < WF4; ++p)
            *(float4*)&Ws[wk0 + p * WKP][wc * 4] = wreg[p];
        __syncthreads();
        // prefetch chunk c+1 (issues vmem; consumed next iteration)
        if (c + 1 < NCHUNK) {
            int kc = (c + 1) * 32;
            #pragma unroll
            for (int p = 0; p < F4PT; ++p)
                areg[p] = *(const float4*)(abase + kc + p * 4);
            #pragma unroll
            for (int p = 0; p < WF4; ++p)
                wreg[p] = *(const float4*)&W[(long)(kc + wk0 + p * WKP) * LDW + n0 + wc * 4];
        }
        // compute chunk c
        #pragma unroll 4
        for (int k = 0; k < 32; ++k) {
            float av[RM], wv[RN];
            #pragma unroll
            for (int i4 = 0; i4 < RM / 4; ++i4) {
                float4 v = *(const float4*)&As[k][ty * RM + i4 * 4];
                av[i4 * 4 + 0] = v.x; av[i4 * 4 + 1] = v.y;
                av[i4 * 4 + 2] = v.z; av[i4 * 4 + 3] = v.w;
            }
            {
                float4 v = *(const float4*)&Ws[k][tx * 4];
                wv[0] = v.x; wv[1] = v.y; wv[2] = v.z; wv[3] = v.w;
                float4 u = *(const float4*)&Ws[k][TN / 2 + tx * 4];
                wv[4] = u.x; wv[5] = u.y; wv[6] = u.z; wv[7] = u.w;
            }
            #pragma unroll
            for (int i = 0; i < RM; ++i)
                #pragma unroll
                for (int j = 0; j < RN; ++j)
                    acc[i][j] = fmaf(av[i], wv[j], acc[i][j]);
        }
        __syncthreads();
    }
    #pragma unroll
    for (int i = 0; i < RM; ++i) {
        int row = m0 + ty * RM + i;
        if (row < M) {
            float4 o0 = {acc[i][0], acc[i][1], acc[i][2], acc[i][3]};
            float4 o1 = {acc[i][4], acc[i][5], acc[i][6], acc[i][7]};
            *(float4*)&C[(long)row * LDC + n0 + tx * 4] = o0;
            *(float4*)&C[(long)row * LDC + n0 + TN / 2 + tx * 4] = o1;
        }
    }
    if (ATT_EP) {
        float asr[RN], adr[RN];
        #pragma unroll
        for (int j = 0; j < RN; ++j) {
            int col = (j < 4) ? (tx * 4 + j) : (TN / 2 + tx * 4 + j - 4);
            asr[j] = att_s[col];
            adr[j] = att_d[col];
        }
        #pragma unroll
        for (int i = 0; i < RM; ++i) {
            float ps = 0.f, pd = 0.f;
            #pragma unroll
            for (int j = 0; j < RN; ++j) {
                ps = fmaf(acc[i][j], asr[j], ps);
                pd = fmaf(acc[i][j], adr[j], pd);
            }
            #pragma unroll
            for (int o = 1; o < NX; o <<= 1) {
                ps += __shfl_xor(ps, o);
                pd += __shfl_xor(pd, o);
            }
            int row = m0 + ty * RM + i;
            if (tx == 0 && row < M) { a_src[row] = ps; a_dst[row] = pd; }
        }
    }
}

// ------- UV precompute: UV4[k] = {U[k,0],U[k,1],V[k,0],V[k,1]} ---------------
__global__ void uv_k(const float* __restrict__ W1, const float* __restrict__ as1,
                     const float* __restrict__ ad1, float* __restrict__ UV4)
{
    int t = threadIdx.x;
    int k = t >> 1, h = t & 1;
    const float* wrow = W1 + (long)k * F1 + h * 128;
    const float* sa = as1 + h * 128;
    const float* da = ad1 + h * 128;
    float u = 0.f, v = 0.f;
    for (int c = 0; c < 128; ++c) {
        float w = wrow[c];
        u = fmaf(w, sa[c], u);
        v = fmaf(w, da[c], v);
    }
    UV4[k * 4 + h] = u;
    UV4[k * 4 + 2 + h] = v;
}

// ------- layer-1 attention scalars -------------------------------------------
__global__ __launch_bounds__(256) void att1v_k(
    const float* __restrict__ x, const float* __restrict__ UV4,
    float* __restrict__ a_src, float* __restrict__ a_dst, int N)
{
    int wave = threadIdx.x >> 6, lane = threadIdx.x & 63;
    int n = blockIdx.x * 4 + wave;
    if (n >= N) return;
    float2 xv = ((const float2*)(x + (long)n * IN_F))[lane];
    float4 u0 = ((const float4*)UV4)[2 * lane];
    float4 u1 = ((const float4*)UV4)[2 * lane + 1];
    float p0 = xv.x * u0.x + xv.y * u1.x;
    float p1 = xv.x * u0.y + xv.y * u1.y;
    float p2 = xv.x * u0.z + xv.y * u1.z;
    float p3 = xv.x * u0.w + xv.y * u1.w;
    #pragma unroll
    for (int o = 32; o > 0; o >>= 1) {
        p0 += __shfl_xor(p0, o); p1 += __shfl_xor(p1, o);
        p2 += __shfl_xor(p2, o); p3 += __shfl_xor(p3, o);
    }
    if (lane == 0) {
        a_src[(long)n * 2 + 0] = p0; a_src[(long)n * 2 + 1] = p1;
        a_dst[(long)n * 2 + 0] = p2; a_dst[(long)n * 2 + 1] = p3;
    }
}

// ---------------- CSR build: histogram -> 3-phase scan -> scatter ------------
__global__ void hist_k(const int* __restrict__ ei_d, int* __restrict__ deg, int E, int Ep)
{
    int i = blockIdx.x * blockDim.x + threadIdx.x;
    if (i >= Ep) return;
    int d = (i < E) ? ei_d[i] : (i - E);
    atomicAdd(&deg[d], 1);
}

__global__ __launch_bounds__(1024) void scanA_k(const int* __restrict__ deg,
                                                int* __restrict__ rowptr,
                                                int* __restrict__ bsum, int N)
{
    __shared__ int wsum[16];
    int t = threadIdx.x, lane = t & 63, w = t >> 6;
    int i = blockIdx.x * 1024 + t;
    int v = (i < N) ? deg[i] : 0;
    int incl = v;
    #pragma unroll
    for (int o = 1; o < 64; o <<= 1) {
        int nb = __shfl_up(incl, o);
        if (lane >= o) incl += nb;
    }
    if (lane == 63) wsum[w] = incl;
    __syncthreads();
    if (w == 0 && lane < 16) {
        int x = wsum[lane];
        #pragma unroll
        for (int o = 1; o < 16; o <<= 1) {
            int nb = __shfl_up(x, o);
            if (lane >= o) x += nb;
        }
        wsum[lane] = x;
    }
    __syncthreads();
    int woff = (w == 0) ? 0 : wsum[w - 1];
    if (i < N) rowptr[i] = woff + incl - v;
    if (t == 1023) bsum[blockIdx.x] = woff + incl;
}

__global__ void scanB_k(int* __restrict__ bsum, int* __restrict__ bex,
                        int* __restrict__ rowptr, int NBLK, int N)
{
    int lane = threadIdx.x & 63;
    int v = (lane < NBLK) ? bsum[lane] : 0;
    int incl = v;
    #pragma unroll
    for (int o = 1; o < 64; o <<= 1) {
        int nb = __shfl_up(incl, o);
        if (lane >= o) incl += nb;
    }
    if (lane < NBLK) bex[lane] = incl - v;
    if (lane == NBLK - 1) rowptr[N] = incl;
}

__global__ __launch_bounds__(1024) void scanC_k(int* __restrict__ rowptr,
                                                const int* __restrict__ bex, int N)
{
    int i = blockIdx.x * 1024 + threadIdx.x;
    if (i < N) rowptr[i] += bex[blockIdx.x];
}

// scatter: also record original edge id (-1 for self-loops) for CSR decode
__global__ void scatter_k(const int* __restrict__ ei_s, const int* __restrict__ ei_d,
                          const int* __restrict__ rowptr, int* __restrict__ cursor,
                          int* __restrict__ csr_src, int* __restrict__ csr_eid,
                          int E, int Ep)
{
    int i = blockIdx.x * blockDim.x + threadIdx.x;
    if (i >= Ep) return;
    int s = (i < E) ? ei_s[i] : (i - E);
    int d = (i < E) ? ei_d[i] : (i - E);
    int pos = atomicAdd(&cursor[d], 1);
    int at = rowptr[d] + pos;
    csr_src[at] = s;
    csr_eid[at] = (i < E) ? i : -1;
}

// ------- layer-1 aggregation in INPUT space ---------------------------------
__global__ __launch_bounds__(256) void agg1x(
    const int* __restrict__ rowptr, const int* __restrict__ csr_src,
    const float* __restrict__ a_s, const float* __restrict__ a_d,  // [N,2]
    const float* __restrict__ x, float* __restrict__ G, int N)
{
    int wave = threadIdx.x >> 6, lane = threadIdx.x & 63;
    int d = blockIdx.x * 4 + wave;
    if (d >= N) return;
    int row = rowptr[d], end = rowptr[d + 1];
    int h = lane >> 5, l5 = lane & 31;
    float adh = a_d[(long)d * 2 + h];
    float a0[4] = {0,0,0,0}, a1[4] = {0,0,0,0};
    float den = 0.f;
    for (int base = row; base < end; base += 32) {
        int cnt = min(32, end - base);
        int sreg = 0; float e = 0.f;
        if (l5 < cnt) {
            sreg = csr_src[base + l5];
            float v = a_s[(long)sreg * 2 + h] + adh;
            v = (v > 0.f) ? v : NEG * v;
            e = expf(v);
            den += e;
        }
        int jmax = (cnt + 1) >> 1;
        for (int j = 0; j < jmax; ++j) {
            int m = 2 * j + h;
            int s = __shfl(sreg, m);
            float w0 = __shfl(e, m);
            float w1 = __shfl(e, 32 | m);
            float4 v = *(const float4*)(x + (long)s * IN_F + l5 * 4);
            a0[0] = fmaf(w0, v.x, a0[0]); a0[1] = fmaf(w0, v.y, a0[1]);
            a0[2] = fmaf(w0, v.z, a0[2]); a0[3] = fmaf(w0, v.w, a0[3]);
            a1[0] = fmaf(w1, v.x, a1[0]); a1[1] = fmaf(w1, v.y, a1[1]);
            a1[2] = fmaf(w1, v.z, a1[2]); a1[3] = fmaf(w1, v.w, a1[3]);
        }
    }
    #pragma unroll
    for (int o = 16; o > 0; o >>= 1) den += __shfl_xor(den, o);
    #pragma unroll
    for (int p = 0; p < 4; ++p) {
        a0[p] += __shfl_xor(a0[p], 32);
        a1[p] += __shfl_xor(a1[p], 32);
    }
    float inv = 1.0f / (den + 1e-16f);
    float* acch = (h == 0) ? a0 : a1;
    float4 o4 = {acch[0] * inv, acch[1] * inv, acch[2] * inv, acch[3] * inv};
    *(float4*)(G + (long)d * F1 + h * 128 + l5 * 4) = o4;
}

// ------- layer-2 aggregation (bias fused into output) ------------------------
__global__ __launch_bounds__(256) void agg2_csr(
    const int* __restrict__ rowptr, const int* __restrict__ csr_src,
    const float* __restrict__ a_s, const float* __restrict__ a_d,  // [N]
    const float* __restrict__ xh2, const float* __restrict__ b2,
    float* __restrict__ out2b, int N)
{
    int wave = threadIdx.x >> 6, lane = threadIdx.x & 63;
    int d = blockIdx.x * 4 + wave;
    if (d >= N) return;
    int row = rowptr[d], end = rowptr[d + 1];
    float adv = a_d[d];
    int g = lane >> 4, q = lane & 15;
    float acc[4] = {0,0,0,0};
    float den = 0.f;
    for (int base = row; base < end; base += 64) {
        int cnt = min(64, end - base);
        float ev = 0.f; int sreg = 0;
        if (lane < cnt) {
            sreg = csr_src[base + lane];
            float v = a_s[sreg] + adv; v = (v > 0.f) ? v : NEG * v;
            ev = expf(v);
            den += ev;
        }
        int jmax = (cnt + 3) >> 2;
        for (int j = 0; j < jmax; ++j) {
            int m = 4 * j + g;
            int s = __shfl(sreg, m);
            float w = __shfl(ev, m);
            float4 v = *(const float4*)(xh2 + (long)s * F2 + q * 4);
            acc[0] = fmaf(w, v.x, acc[0]); acc[1] = fmaf(w, v.y, acc[1]);
            acc[2] = fmaf(w, v.z, acc[2]); acc[3] = fmaf(w, v.w, acc[3]);
        }
    }
    #pragma unroll
    for (int o = 32; o > 0; o >>= 1) den += __shfl_xor(den, o);
    #pragma unroll
    for (int p = 0; p < 4; ++p) {
        acc[p] += __shfl_xor(acc[p], 16);
        acc[p] += __shfl_xor(acc[p], 32);
    }
    if (g == 0) {
        float inv = 1.0f / (den + 1e-16f);
        float4 bb = *(const float4*)&b2[q * 4];
        float4 o4 = {acc[0] * inv + bb.x, acc[1] * inv + bb.y,
                     acc[2] * inv + bb.z, acc[3] * inv + bb.w};
        *(float4*)(out2b + (long)d * F2 + q * 4) = o4;
    }
}

// ------- decode via CSR: z2b[d] loaded once per node, src-side gathered ------
__global__ __launch_bounds__(256) void decode_csr(
    const int* __restrict__ rowptr, const int* __restrict__ csr_src,
    const int* __restrict__ csr_eid, const float* __restrict__ z2b,
    float* __restrict__ out, int N)
{
    int wave = threadIdx.x >> 6, lane = threadIdx.x & 63;
    int d = blockIdx.x * 4 + wave;
    if (d >= N) return;
    int row = rowptr[d], end = rowptr[d + 1];
    int g = lane >> 4, q = lane & 15;
    float4 vd = *(const float4*)(z2b + (long)d * F2 + q * 4);
    for (int base = row; base < end; base += 64) {
        int cnt = min(64, end - base);
        int sreg = 0, ereg = -1;
        if (lane < cnt) {
            sreg = csr_src[base + lane];
            ereg = csr_eid[base + lane];
        }
        int jmax = (cnt + 3) >> 2;
        for (int j = 0; j < jmax; ++j) {
            int m = 4 * j + g;
            int s = __shfl(sreg, m);
            int eid = __shfl(ereg, m);
            float4 vs = *(const float4*)(z2b + (long)s * F2 + q * 4);
            float p = vd.x * vs.x + vd.y * vs.y + vd.z * vs.z + vd.w * vs.w;
            #pragma unroll
            for (int o = 1; o < 16; o <<= 1) p += __shfl_xor(p, o);
            if (q == 0 && eid >= 0) out[eid] = p;
        }
    }
}

extern "C" void kernel_launch(void* const* d_in, const int* in_sizes, int n_in,
                              void* d_out, int out_size, void* d_ws, size_t ws_size,
                              hipStream_t stream) {
    const float* x   = (const float*)d_in[0];
    const int*   ei  = (const int*)d_in[1];
    const float* W1  = (const float*)d_in[2];
    const float* as1 = (const float*)d_in[3];
    const float* ad1 = (const float*)d_in[4];
    const float* b1  = (const float*)d_in[5];
    const float* W2  = (const float*)d_in[6];
    const float* as2 = (const float*)d_in[7];
    const float* ad2 = (const float*)d_in[8];
    const float* b2  = (const float*)d_in[9];

    int N  = in_sizes[0] / IN_F;   // 50000
    int E  = in_sizes[1] / 2;      // 600000
    int Ep = E + N;
    const int* ei_src = ei;
    const int* ei_dst = ei + E;

    float* ws = (float*)d_ws;
    size_t off = 0;
    auto alloc = [&](size_t n) { float* p = ws + off; off += (n + 63) & ~(size_t)63; return p; };

    float* G      = alloc((size_t)N * F1);
    float* z1     = alloc((size_t)N * F1);
    float* xh2    = alloc((size_t)N * F2);
    float* out2b  = alloc((size_t)N * F2);
    float* a_src1 = alloc((size_t)N * H1);
    float* a_dst1 = alloc((size_t)N * H1);
    float* a_src2 = alloc(N);
    float* a_dst2 = alloc(N);
    float* UV4    = alloc(IN_F * 4);
    int* rowptr   = (int*)alloc(N + 64);
    int* csr_src  = (int*)alloc(Ep);
    int* csr_eid  = (int*)alloc(Ep);
    int* bsum     = (int*)alloc(64);
    int* bex      = (int*)alloc(64);
    int* deg      = (int*)alloc(N);
    int* cursor   = (int*)alloc(N);
    hipMemsetAsync(deg, 0, ((size_t)(cursor + N) - (size_t)deg), stream);

    int NBLK = (N + 1023) / 1024;   // 49
    // CSR build
    hist_k<<<(Ep + 255) / 256, 256, 0, stream>>>(ei_dst, deg, E, Ep);
    scanA_k<<<NBLK, 1024, 0, stream>>>(deg, rowptr, bsum, N);
    scanB_k<<<1, 64, 0, stream>>>(bsum, bex, rowptr, NBLK, N);
    scanC_k<<<NBLK, 1024, 0, stream>>>(rowptr, bex, N);
    scatter_k<<<(Ep + 255) / 256, 256, 0, stream>>>(ei_src, ei_dst, rowptr, cursor,
                                                    csr_src, csr_eid, E, Ep);

    // layer 1: attention scalars from x directly, aggregate x, then GEMM
    uv_k<<<1, 256, 0, stream>>>(W1, as1, ad1, UV4);
    att1v_k<<<(N + 3) / 4, 256, 0, stream>>>(x, UV4, a_src1, a_dst1, N);
    agg1x<<<(N + 3) / 4, 256, 0, stream>>>(rowptr, csr_src, a_src1, a_dst1, x, G, N);
    // z1[:, h*128..] = G[:, h*128..] @ W1[:, h*128..], h = blockIdx.y
    int mt1 = (N + 127) / 128;
    gemm_tiled<IN_F, 128, 128, 8, 8, F1, F1, F1, false, false, true>
        <<<dim3(mt1, 2), 256, 0, stream>>>(
        G, nullptr, W1, z1, nullptr, nullptr, nullptr, nullptr, N);

    // layer 2
    gemm_tiled<F1, 128, 64, 4, 8, F1, F2, F2, true, true, false>
        <<<dim3(mt1, 1), 256, 0, stream>>>(
        z1, b1, W2, xh2, as2, ad2, a_src2, a_dst2, N);
    agg2_csr<<<(N + 3) / 4, 256, 0, stream>>>(rowptr, csr_src, a_src2, a_dst2, xh2, b2, out2b, N);

    // decode via CSR
    decode_csr<<<(N + 3) / 4, 256, 0, stream>>>(rowptr, csr_src, csr_eid, out2b,
                                                (float*)d_out, N);
}

// Round 11
// 348.428 us; speedup vs baseline: 1.0967x; 1.0967x over previous
//
#include <hip/hip_runtime.h>
#include <math.h>

#define IN_F 128
#define F1 256   // H1*C1
#define H1 2
#define F2 64
#define NEG 0.2f

// ---------------- tiled fp32 GEMM (round-9 best: no prefetch, split-col) -----
template<int KTOT, int TM, int TN, int RM, int RN, int LDA, int LDW, int LDC,
         bool RELU, bool ATT_EP, bool HEADOFF>
__global__ __launch_bounds__(256) void gemm_tiled(
    const float* __restrict__ A, const float* __restrict__ bias,
    const float* __restrict__ W, float* __restrict__ C,
    const float* __restrict__ att_s, const float* __restrict__ att_d,
    float* __restrict__ a_src, float* __restrict__ a_dst, int M)
{
    constexpr int NX = TN / RN;
    constexpr int NY = 256 / NX;
    static_assert(NY * RM == TM, "tile mismatch");
    static_assert(RN == 8, "split-col mapping assumes RN==8");
    __shared__ float As[32][TM];
    __shared__ float Ws[32][TN];
    int t = threadIdx.x;
    int tx = t % NX, ty = t / NX;
    int m0 = blockIdx.x * TM;
    int n0 = blockIdx.y * TN;
    long aoff = HEADOFF ? (long)blockIdx.y * KTOT : 0;
    float acc[RM][RN];
    #pragma unroll
    for (int i = 0; i < RM; ++i)
        #pragma unroll
        for (int j = 0; j < RN; ++j) acc[i][j] = 0.f;

    constexpr int PARTS = 256 / TM;
    constexpr int F4PT = 8 / PARTS;
    int ar = t % TM, apart = t / TM;
    int arow = m0 + ar; if (arow >= M) arow = M - 1;
    constexpr int WTPK = TN / 4;
    constexpr int WKP = 256 / WTPK;
    int wk0 = t / WTPK, wc = t % WTPK;

    for (int kc = 0; kc < KTOT; kc += 32) {
        const float* ap = A + (long)arow * LDA + aoff + kc + apart * (F4PT * 4);
        #pragma unroll
        for (int p = 0; p < F4PT; ++p) {
            int kk = apart * (F4PT * 4) + p * 4;
            float4 v = *(const float4*)(ap + p * 4);
            if (RELU) {
                float4 bb = *(const float4*)&bias[kc + kk];
                v.x = fmaxf(v.x + bb.x, 0.f);
                v.y = fmaxf(v.y + bb.y, 0.f);
                v.z = fmaxf(v.z + bb.z, 0.f);
                v.w = fmaxf(v.w + bb.w, 0.f);
            }
            As[kk + 0][ar] = v.x;
            As[kk + 1][ar] = v.y;
            As[kk + 2][ar] = v.z;
            As[kk + 3][ar] = v.w;
        }
        #pragma unroll
        for (int p = 0; p < 32 / WKP; ++p) {
            int k = wk0 + p * WKP;
            *(float4*)&Ws[k][wc * 4] =
                *(const float4*)&W[(long)(kc + k) * LDW + n0 + wc * 4];
        }
        __syncthreads();
        #pragma unroll 4
        for (int k = 0; k < 32; ++k) {
            float av[RM], wv[RN];
            #pragma unroll
            for (int i4 = 0; i4 < RM / 4; ++i4) {
                float4 v = *(const float4*)&As[k][ty * RM + i4 * 4];
                av[i4 * 4 + 0] = v.x; av[i4 * 4 + 1] = v.y;
                av[i4 * 4 + 2] = v.z; av[i4 * 4 + 3] = v.w;
            }
            {
                float4 v = *(const float4*)&Ws[k][tx * 4];
                wv[0] = v.x; wv[1] = v.y; wv[2] = v.z; wv[3] = v.w;
                float4 u = *(const float4*)&Ws[k][TN / 2 + tx * 4];
                wv[4] = u.x; wv[5] = u.y; wv[6] = u.z; wv[7] = u.w;
            }
            #pragma unroll
            for (int i = 0; i < RM; ++i)
                #pragma unroll
                for (int j = 0; j < RN; ++j)
                    acc[i][j] = fmaf(av[i], wv[j], acc[i][j]);
        }
        __syncthreads();
    }
    #pragma unroll
    for (int i = 0; i < RM; ++i) {
        int row = m0 + ty * RM + i;
        if (row < M) {
            float4 o0 = {acc[i][0], acc[i][1], acc[i][2], acc[i][3]};
            float4 o1 = {acc[i][4], acc[i][5], acc[i][6], acc[i][7]};
            *(float4*)&C[(long)row * LDC + n0 + tx * 4] = o0;
            *(float4*)&C[(long)row * LDC + n0 + TN / 2 + tx * 4] = o1;
        }
    }
    if (ATT_EP) {
        float asr[RN], adr[RN];
        #pragma unroll
        for (int j = 0; j < RN; ++j) {
            int col = (j < 4) ? (tx * 4 + j) : (TN / 2 + tx * 4 + j - 4);
            asr[j] = att_s[col];
            adr[j] = att_d[col];
        }
        #pragma unroll
        for (int i = 0; i < RM; ++i) {
            float ps = 0.f, pd = 0.f;
            #pragma unroll
            for (int j = 0; j < RN; ++j) {
                ps = fmaf(acc[i][j], asr[j], ps);
                pd = fmaf(acc[i][j], adr[j], pd);
            }
            #pragma unroll
            for (int o = 1; o < NX; o <<= 1) {
                ps += __shfl_xor(ps, o);
                pd += __shfl_xor(pd, o);
            }
            int row = m0 + ty * RM + i;
            if (tx == 0 && row < M) { a_src[row] = ps; a_dst[row] = pd; }
        }
    }
}

// ------- launch 1: histogram w/ position recording + UV precompute -----------
// blocks [0, NBH): pos[i] = slot of edge i within its dst bucket.
// block NBH: UV4[k] = {U[k,0],U[k,1],V[k,0],V[k,1]}, U=W1·att_s per head.
__global__ __launch_bounds__(256) void hist_uv_k(
    const int* __restrict__ ei_d, int* __restrict__ deg, int* __restrict__ pos,
    int E, int Ep, int NBH,
    const float* __restrict__ W1, const float* __restrict__ as1,
    const float* __restrict__ ad1, float* __restrict__ UV4)
{
    if ((int)blockIdx.x < NBH) {
        int i = blockIdx.x * 256 + threadIdx.x;
        if (i >= Ep) return;
        int d = (i < E) ? ei_d[i] : (i - E);
        pos[i] = atomicAdd(&deg[d], 1);
    } else {
        int t = threadIdx.x;
        int k = t >> 1, h = t & 1;
        const float* wrow = W1 + (long)k * F1 + h * 128;
        const float* sa = as1 + h * 128;
        const float* da = ad1 + h * 128;
        float u = 0.f, v = 0.f;
        for (int c = 0; c < 128; ++c) {
            float w = wrow[c];
            u = fmaf(w, sa[c], u);
            v = fmaf(w, da[c], v);
        }
        UV4[k * 4 + h] = u;
        UV4[k * 4 + 2 + h] = v;
    }
}

// ------- launch 2: per-block scan (blocks [0,NBLK)) + att1v (rest) -----------
__global__ __launch_bounds__(1024) void scanA_att_k(
    const int* __restrict__ deg, int* __restrict__ rowptr, int* __restrict__ bsum,
    int N, int NBLK,
    const float* __restrict__ x, const float* __restrict__ UV4,
    float* __restrict__ a_src, float* __restrict__ a_dst)
{
    if ((int)blockIdx.x < NBLK) {
        __shared__ int wsum[16];
        int t = threadIdx.x, lane = t & 63, w = t >> 6;
        int i = blockIdx.x * 1024 + t;
        int v = (i < N) ? deg[i] : 0;
        int incl = v;
        #pragma unroll
        for (int o = 1; o < 64; o <<= 1) {
            int nb = __shfl_up(incl, o);
            if (lane >= o) incl += nb;
        }
        if (lane == 63) wsum[w] = incl;
        __syncthreads();
        if (w == 0 && lane < 16) {
            int s = wsum[lane];
            #pragma unroll
            for (int o = 1; o < 16; o <<= 1) {
                int nb = __shfl_up(s, o);
                if (lane >= o) s += nb;
            }
            wsum[lane] = s;
        }
        __syncthreads();
        int woff = (w == 0) ? 0 : wsum[w - 1];
        if (i < N) rowptr[i] = woff + incl - v;
        if (t == 1023) bsum[blockIdx.x] = woff + incl;
    } else {
        int wave = threadIdx.x >> 6, lane = threadIdx.x & 63;
        int n = ((int)blockIdx.x - NBLK) * 16 + wave;
        if (n >= N) return;
        float2 xv = ((const float2*)(x + (long)n * IN_F))[lane];
        float4 u0 = ((const float4*)UV4)[2 * lane];
        float4 u1 = ((const float4*)UV4)[2 * lane + 1];
        float p0 = xv.x * u0.x + xv.y * u1.x;
        float p1 = xv.x * u0.y + xv.y * u1.y;
        float p2 = xv.x * u0.z + xv.y * u1.z;
        float p3 = xv.x * u0.w + xv.y * u1.w;
        #pragma unroll
        for (int o = 32; o > 0; o >>= 1) {
            p0 += __shfl_xor(p0, o); p1 += __shfl_xor(p1, o);
            p2 += __shfl_xor(p2, o); p3 += __shfl_xor(p3, o);
        }
        if (lane == 0) {
            a_src[(long)n * 2 + 0] = p0; a_src[(long)n * 2 + 1] = p1;
            a_dst[(long)n * 2 + 0] = p2; a_dst[(long)n * 2 + 1] = p3;
        }
    }
}

// ------- launch 3: add block offsets (each block re-scans the <=64 bsums) ----
__global__ __launch_bounds__(1024) void scanC2_k(
    int* __restrict__ rowptr, const int* __restrict__ bsum, int NBLK, int N)
{
    __shared__ int bex_sh, tot_sh;
    int t = threadIdx.x;
    if (t < 64) {
        int lane = t;
        int v = (lane < NBLK) ? bsum[lane] : 0;
        int incl = v;
        #pragma unroll
        for (int o = 1; o < 64; o <<= 1) {
            int nb = __shfl_up(incl, o);
            if (lane >= o) incl += nb;
        }
        if (lane == (int)blockIdx.x) bex_sh = incl - v;
        if (lane == NBLK - 1) tot_sh = incl;
    }
    __syncthreads();
    int i = blockIdx.x * 1024 + t;
    if (i < N) rowptr[i] += bex_sh;
    if ((int)blockIdx.x == NBLK - 1 && t == 0) rowptr[N] = tot_sh;
}

// ------- launch 4: atomic-free scatter using recorded positions --------------
__global__ void scatter_nc(const int* __restrict__ ei_s, const int* __restrict__ ei_d,
                           const int* __restrict__ rowptr, const int* __restrict__ pos,
                           int* __restrict__ csr_src, int* __restrict__ csr_eid,
                           int E, int Ep)
{
    int i = blockIdx.x * blockDim.x + threadIdx.x;
    if (i >= Ep) return;
    int s = (i < E) ? ei_s[i] : (i - E);
    int d = (i < E) ? ei_d[i] : (i - E);
    int at = rowptr[d] + pos[i];
    csr_src[at] = s;
    csr_eid[at] = (i < E) ? i : -1;
}

// ------- layer-1 aggregation in INPUT space ---------------------------------
__global__ __launch_bounds__(256) void agg1x(
    const int* __restrict__ rowptr, const int* __restrict__ csr_src,
    const float* __restrict__ a_s, const float* __restrict__ a_d,  // [N,2]
    const float* __restrict__ x, float* __restrict__ G, int N)
{
    int wave = threadIdx.x >> 6, lane = threadIdx.x & 63;
    int d = blockIdx.x * 4 + wave;
    if (d >= N) return;
    int row = rowptr[d], end = rowptr[d + 1];
    int h = lane >> 5, l5 = lane & 31;
    float adh = a_d[(long)d * 2 + h];
    float a0[4] = {0,0,0,0}, a1[4] = {0,0,0,0};
    float den = 0.f;
    for (int base = row; base < end; base += 32) {
        int cnt = min(32, end - base);
        int sreg = 0; float e = 0.f;
        if (l5 < cnt) {
            sreg = csr_src[base + l5];
            float v = a_s[(long)sreg * 2 + h] + adh;
            v = (v > 0.f) ? v : NEG * v;
            e = expf(v);
            den += e;
        }
        int jmax = (cnt + 1) >> 1;
        for (int j = 0; j < jmax; ++j) {
            int m = 2 * j + h;
            int s = __shfl(sreg, m);
            float w0 = __shfl(e, m);
            float w1 = __shfl(e, 32 | m);
            float4 v = *(const float4*)(x + (long)s * IN_F + l5 * 4);
            a0[0] = fmaf(w0, v.x, a0[0]); a0[1] = fmaf(w0, v.y, a0[1]);
            a0[2] = fmaf(w0, v.z, a0[2]); a0[3] = fmaf(w0, v.w, a0[3]);
            a1[0] = fmaf(w1, v.x, a1[0]); a1[1] = fmaf(w1, v.y, a1[1]);
            a1[2] = fmaf(w1, v.z, a1[2]); a1[3] = fmaf(w1, v.w, a1[3]);
        }
    }
    #pragma unroll
    for (int o = 16; o > 0; o >>= 1) den += __shfl_xor(den, o);
    #pragma unroll
    for (int p = 0; p < 4; ++p) {
        a0[p] += __shfl_xor(a0[p], 32);
        a1[p] += __shfl_xor(a1[p], 32);
    }
    float inv = 1.0f / (den + 1e-16f);
    float* acch = (h == 0) ? a0 : a1;
    float4 o4 = {acch[0] * inv, acch[1] * inv, acch[2] * inv, acch[3] * inv};
    *(float4*)(G + (long)d * F1 + h * 128 + l5 * 4) = o4;
}

// ------- layer-2 aggregation (bias fused into output) ------------------------
__global__ __launch_bounds__(256) void agg2_csr(
    const int* __restrict__ rowptr, const int* __restrict__ csr_src,
    const float* __restrict__ a_s, const float* __restrict__ a_d,  // [N]
    const float* __restrict__ xh2, const float* __restrict__ b2,
    float* __restrict__ out2b, int N)
{
    int wave = threadIdx.x >> 6, lane = threadIdx.x & 63;
    int d = blockIdx.x * 4 + wave;
    if (d >= N) return;
    int row = rowptr[d], end = rowptr[d + 1];
    float adv = a_d[d];
    int g = lane >> 4, q = lane & 15;
    float acc[4] = {0,0,0,0};
    float den = 0.f;
    for (int base = row; base < end; base += 64) {
        int cnt = min(64, end - base);
        float ev = 0.f; int sreg = 0;
        if (lane < cnt) {
            sreg = csr_src[base + lane];
            float v = a_s[sreg] + adv; v = (v > 0.f) ? v : NEG * v;
            ev = expf(v);
            den += ev;
        }
        int jmax = (cnt + 3) >> 2;
        for (int j = 0; j < jmax; ++j) {
            int m = 4 * j + g;
            int s = __shfl(sreg, m);
            float w = __shfl(ev, m);
            float4 v = *(const float4*)(xh2 + (long)s * F2 + q * 4);
            acc[0] = fmaf(w, v.x, acc[0]); acc[1] = fmaf(w, v.y, acc[1]);
            acc[2] = fmaf(w, v.z, acc[2]); acc[3] = fmaf(w, v.w, acc[3]);
        }
    }
    #pragma unroll
    for (int o = 32; o > 0; o >>= 1) den += __shfl_xor(den, o);
    #pragma unroll
    for (int p = 0; p < 4; ++p) {
        acc[p] += __shfl_xor(acc[p], 16);
        acc[p] += __shfl_xor(acc[p], 32);
    }
    if (g == 0) {
        float inv = 1.0f / (den + 1e-16f);
        float4 bb = *(const float4*)&b2[q * 4];
        float4 o4 = {acc[0] * inv + bb.x, acc[1] * inv + bb.y,
                     acc[2] * inv + bb.z, acc[3] * inv + bb.w};
        *(float4*)(out2b + (long)d * F2 + q * 4) = o4;
    }
}

// ------- decode via CSR ------------------------------------------------------
__global__ __launch_bounds__(256) void decode_csr(
    const int* __restrict__ rowptr, const int* __restrict__ csr_src,
    const int* __restrict__ csr_eid, const float* __restrict__ z2b,
    float* __restrict__ out, int N)
{
    int wave = threadIdx.x >> 6, lane = threadIdx.x & 63;
    int d = blockIdx.x * 4 + wave;
    if (d >= N) return;
    int row = rowptr[d], end = rowptr[d + 1];
    int g = lane >> 4, q = lane & 15;
    float4 vd = *(const float4*)(z2b + (long)d * F2 + q * 4);
    for (int base = row; base < end; base += 64) {
        int cnt = min(64, end - base);
        int sreg = 0, ereg = -1;
        if (lane < cnt) {
            sreg = csr_src[base + lane];
            ereg = csr_eid[base + lane];
        }
        int jmax = (cnt + 3) >> 2;
        for (int j = 0; j < jmax; ++j) {
            int m = 4 * j + g;
            int s = __shfl(sreg, m);
            int eid = __shfl(ereg, m);
            float4 vs = *(const float4*)(z2b + (long)s * F2 + q * 4);
            float p = vd.x * vs.x + vd.y * vs.y + vd.z * vs.z + vd.w * vs.w;
            #pragma unroll
            for (int o = 1; o < 16; o <<= 1) p += __shfl_xor(p, o);
            if (q == 0 && eid >= 0) out[eid] = p;
        }
    }
}

extern "C" void kernel_launch(void* const* d_in, const int* in_sizes, int n_in,
                              void* d_out, int out_size, void* d_ws, size_t ws_size,
                              hipStream_t stream) {
    const float* x   = (const float*)d_in[0];
    const int*   ei  = (const int*)d_in[1];
    const float* W1  = (const float*)d_in[2];
    const float* as1 = (const float*)d_in[3];
    const float* ad1 = (const float*)d_in[4];
    const float* b1  = (const float*)d_in[5];
    const float* W2  = (const float*)d_in[6];
    const float* as2 = (const float*)d_in[7];
    const float* ad2 = (const float*)d_in[8];
    const float* b2  = (const float*)d_in[9];

    int N  = in_sizes[0] / IN_F;   // 50000
    int E  = in_sizes[1] / 2;      // 600000
    int Ep = E + N;
    const int* ei_src = ei;
    const int* ei_dst = ei + E;

    float* ws = (float*)d_ws;
    size_t off = 0;
    auto alloc = [&](size_t n) { float* p = ws + off; off += (n + 63) & ~(size_t)63; return p; };

    float* G      = alloc((size_t)N * F1);
    float* z1     = alloc((size_t)N * F1);
    float* xh2    = alloc((size_t)N * F2);
    float* out2b  = alloc((size_t)N * F2);
    float* a_src1 = alloc((size_t)N * H1);
    float* a_dst1 = alloc((size_t)N * H1);
    float* a_src2 = alloc(N);
    float* a_dst2 = alloc(N);
    float* UV4    = alloc(IN_F * 4);
    int* rowptr   = (int*)alloc(N + 64);
    int* csr_src  = (int*)alloc(Ep);
    int* csr_eid  = (int*)alloc(Ep);
    int* pos      = (int*)alloc(Ep);
    int* bsum     = (int*)alloc(64);
    int* deg      = (int*)alloc(N);
    hipMemsetAsync(deg, 0, (size_t)N * sizeof(int), stream);

    int NBLK = (N + 1023) / 1024;       // 49
    int NBH  = (Ep + 255) / 256;        // 2540 hist blocks
    int NBA  = (N + 15) / 16;           // 3125 att blocks (16 nodes ea, 1024 thr)

    // launch 1: histogram+pos recording, plus UV precompute (1 extra block)
    hist_uv_k<<<NBH + 1, 256, 0, stream>>>(ei_dst, deg, pos, E, Ep, NBH,
                                           W1, as1, ad1, UV4);
    // launch 2: per-block scan + att1v scalars
    scanA_att_k<<<NBLK + NBA, 1024, 0, stream>>>(deg, rowptr, bsum, N, NBLK,
                                                 x, UV4, a_src1, a_dst1);
    // launch 3: block-offset fixup (inlines the bsum scan per block)
    scanC2_k<<<NBLK, 1024, 0, stream>>>(rowptr, bsum, NBLK, N);
    // launch 4: atomic-free scatter
    scatter_nc<<<NBH, 256, 0, stream>>>(ei_src, ei_dst, rowptr, pos,
                                        csr_src, csr_eid, E, Ep);

    // layer 1: aggregate x in input space, then per-head GEMM
    agg1x<<<(N + 3) / 4, 256, 0, stream>>>(rowptr, csr_src, a_src1, a_dst1, x, G, N);
    int mt1 = (N + 127) / 128;
    gemm_tiled<IN_F, 128, 128, 8, 8, F1, F1, F1, false, false, true>
        <<<dim3(mt1, 2), 256, 0, stream>>>(
        G, nullptr, W1, z1, nullptr, nullptr, nullptr, nullptr, N);

    // layer 2
    gemm_tiled<F1, 128, 64, 4, 8, F1, F2, F2, true, true, false>
        <<<dim3(mt1, 1), 256, 0, stream>>>(
        z1, b1, W2, xh2, as2, ad2, a_src2, a_dst2, N);
    agg2_csr<<<(N + 3) / 4, 256, 0, stream>>>(rowptr, csr_src, a_src2, a_dst2, xh2, b2, out2b, N);

    // decode via CSR
    decode_csr<<<(N + 3) / 4, 256, 0, stream>>>(rowptr, csr_src, csr_eid, out2b,
                                                (float*)d_out, N);
}

// Round 12
// 345.951 us; speedup vs baseline: 1.1046x; 1.0072x over previous
//
#include <hip/hip_runtime.h>
#include <math.h>

#define IN_F 128
#define F1 256   // H1*C1
#define H1 2
#define F2 64
#define NEG 0.2f

// ------- GEMM, W-resident variant: W fully staged in LDS (ONE barrier), -----
// A streamed global->regs with quad double-buffer. No K-loop barriers, so no
// vmcnt(0)+s_barrier drain per chunk (the stall that pinned 5 prior configs
// at ~54us). Within a wave the NX tx-lanes read identical A addresses ->
// hardware broadcast, so A global traffic stays one-read-per-block.
template<int KTOT, int TM, int TN, int RM, int RN, int LDA, int LDW, int LDC,
         bool RELU, bool ATT_EP, bool HEADOFF>
__global__ __launch_bounds__(256) void gemm_wlds(
    const float* __restrict__ A, const float* __restrict__ bias,
    const float* __restrict__ W, float* __restrict__ C,
    const float* __restrict__ att_s, const float* __restrict__ att_d,
    float* __restrict__ a_src, float* __restrict__ a_dst, int M)
{
    constexpr int NX = TN / RN;
    constexpr int NY = 256 / NX;
    static_assert(NY * RM == TM, "tile mismatch");
    static_assert(RN == 8, "split-col mapping assumes RN==8");
    __shared__ float Ws[KTOT][TN];   // 64 KB for both instantiations
    int t = threadIdx.x;
    int tx = t % NX, ty = t / NX;
    int m0 = blockIdx.x * TM;
    int n0 = blockIdx.y * TN;
    long aoff = HEADOFF ? (long)blockIdx.y * KTOT : 0;

    // stage all of W (coalesced float4), one barrier total
    constexpr int TOT4 = KTOT * TN / 4;
    #pragma unroll
    for (int p = 0; p < TOT4 / 256; ++p) {
        int idx = p * 256 + t;
        int k = idx / (TN / 4);
        int c = idx % (TN / 4);
        *(float4*)&Ws[k][c * 4] = *(const float4*)&W[(long)k * LDW + n0 + c * 4];
    }
    __syncthreads();

    const float* ap[RM];
    #pragma unroll
    for (int i = 0; i < RM; ++i) {
        int r = m0 + ty * RM + i;
        if (r >= M) r = M - 1;
        ap[i] = A + (long)r * LDA + aoff;
    }
    float acc[RM][RN];
    #pragma unroll
    for (int i = 0; i < RM; ++i)
        #pragma unroll
        for (int j = 0; j < RN; ++j) acc[i][j] = 0.f;

    float4 cur[RM], nxt[RM];
    #pragma unroll
    for (int i = 0; i < RM; ++i) cur[i] = *(const float4*)(ap[i]);

    for (int kq = 0; kq < KTOT / 4; ++kq) {
        if (kq + 1 < KTOT / 4) {
            #pragma unroll
            for (int i = 0; i < RM; ++i)
                nxt[i] = *(const float4*)(ap[i] + (kq + 1) * 4);
        }
        if (RELU) {
            float4 bq = *(const float4*)&bias[kq * 4];
            #pragma unroll
            for (int i = 0; i < RM; ++i) {
                cur[i].x = fmaxf(cur[i].x + bq.x, 0.f);
                cur[i].y = fmaxf(cur[i].y + bq.y, 0.f);
                cur[i].z = fmaxf(cur[i].z + bq.z, 0.f);
                cur[i].w = fmaxf(cur[i].w + bq.w, 0.f);
            }
        }
        #pragma unroll
        for (int kk = 0; kk < 4; ++kk) {
            int k = kq * 4 + kk;
            float wv[RN];
            {
                float4 v = *(const float4*)&Ws[k][tx * 4];
                wv[0] = v.x; wv[1] = v.y; wv[2] = v.z; wv[3] = v.w;
                float4 u = *(const float4*)&Ws[k][TN / 2 + tx * 4];
                wv[4] = u.x; wv[5] = u.y; wv[6] = u.z; wv[7] = u.w;
            }
            #pragma unroll
            for (int i = 0; i < RM; ++i) {
                const float* cf = (const float*)&cur[i];
                float a = cf[kk];
                #pragma unroll
                for (int j = 0; j < RN; ++j)
                    acc[i][j] = fmaf(a, wv[j], acc[i][j]);
            }
        }
        #pragma unroll
        for (int i = 0; i < RM; ++i) cur[i] = nxt[i];
    }

    #pragma unroll
    for (int i = 0; i < RM; ++i) {
        int row = m0 + ty * RM + i;
        if (row < M) {
            float4 o0 = {acc[i][0], acc[i][1], acc[i][2], acc[i][3]};
            float4 o1 = {acc[i][4], acc[i][5], acc[i][6], acc[i][7]};
            *(float4*)&C[(long)row * LDC + n0 + tx * 4] = o0;
            *(float4*)&C[(long)row * LDC + n0 + TN / 2 + tx * 4] = o1;
        }
    }
    if (ATT_EP) {
        float asr[RN], adr[RN];
        #pragma unroll
        for (int j = 0; j < RN; ++j) {
            int col = (j < 4) ? (tx * 4 + j) : (TN / 2 + tx * 4 + j - 4);
            asr[j] = att_s[col];
            adr[j] = att_d[col];
        }
        #pragma unroll
        for (int i = 0; i < RM; ++i) {
            float ps = 0.f, pd = 0.f;
            #pragma unroll
            for (int j = 0; j < RN; ++j) {
                ps = fmaf(acc[i][j], asr[j], ps);
                pd = fmaf(acc[i][j], adr[j], pd);
            }
            #pragma unroll
            for (int o = 1; o < NX; o <<= 1) {
                ps += __shfl_xor(ps, o);
                pd += __shfl_xor(pd, o);
            }
            int row = m0 + ty * RM + i;
            if (tx == 0 && row < M) { a_src[row] = ps; a_dst[row] = pd; }
        }
    }
}

// ------- launch 1: histogram w/ position recording + UV precompute -----------
__global__ __launch_bounds__(256) void hist_uv_k(
    const int* __restrict__ ei_d, int* __restrict__ deg, int* __restrict__ pos,
    int E, int Ep, int NBH,
    const float* __restrict__ W1, const float* __restrict__ as1,
    const float* __restrict__ ad1, float* __restrict__ UV4)
{
    if ((int)blockIdx.x < NBH) {
        int i = blockIdx.x * 256 + threadIdx.x;
        if (i >= Ep) return;
        int d = (i < E) ? ei_d[i] : (i - E);
        pos[i] = atomicAdd(&deg[d], 1);
    } else {
        int t = threadIdx.x;
        int k = t >> 1, h = t & 1;
        const float* wrow = W1 + (long)k * F1 + h * 128;
        const float* sa = as1 + h * 128;
        const float* da = ad1 + h * 128;
        float u = 0.f, v = 0.f;
        for (int c = 0; c < 128; ++c) {
            float w = wrow[c];
            u = fmaf(w, sa[c], u);
            v = fmaf(w, da[c], v);
        }
        UV4[k * 4 + h] = u;
        UV4[k * 4 + 2 + h] = v;
    }
}

// ------- launch 2: per-block scan (blocks [0,NBLK)) + att1v (rest) -----------
__global__ __launch_bounds__(1024) void scanA_att_k(
    const int* __restrict__ deg, int* __restrict__ rowptr, int* __restrict__ bsum,
    int N, int NBLK,
    const float* __restrict__ x, const float* __restrict__ UV4,
    float* __restrict__ a_src, float* __restrict__ a_dst)
{
    if ((int)blockIdx.x < NBLK) {
        __shared__ int wsum[16];
        int t = threadIdx.x, lane = t & 63, w = t >> 6;
        int i = blockIdx.x * 1024 + t;
        int v = (i < N) ? deg[i] : 0;
        int incl = v;
        #pragma unroll
        for (int o = 1; o < 64; o <<= 1) {
            int nb = __shfl_up(incl, o);
            if (lane >= o) incl += nb;
        }
        if (lane == 63) wsum[w] = incl;
        __syncthreads();
        if (w == 0 && lane < 16) {
            int s = wsum[lane];
            #pragma unroll
            for (int o = 1; o < 16; o <<= 1) {
                int nb = __shfl_up(s, o);
                if (lane >= o) s += nb;
            }
            wsum[lane] = s;
        }
        __syncthreads();
        int woff = (w == 0) ? 0 : wsum[w - 1];
        if (i < N) rowptr[i] = woff + incl - v;
        if (t == 1023) bsum[blockIdx.x] = woff + incl;
    } else {
        int wave = threadIdx.x >> 6, lane = threadIdx.x & 63;
        int n = ((int)blockIdx.x - NBLK) * 16 + wave;
        if (n >= N) return;
        float2 xv = ((const float2*)(x + (long)n * IN_F))[lane];
        float4 u0 = ((const float4*)UV4)[2 * lane];
        float4 u1 = ((const float4*)UV4)[2 * lane + 1];
        float p0 = xv.x * u0.x + xv.y * u1.x;
        float p1 = xv.x * u0.y + xv.y * u1.y;
        float p2 = xv.x * u0.z + xv.y * u1.z;
        float p3 = xv.x * u0.w + xv.y * u1.w;
        #pragma unroll
        for (int o = 32; o > 0; o >>= 1) {
            p0 += __shfl_xor(p0, o); p1 += __shfl_xor(p1, o);
            p2 += __shfl_xor(p2, o); p3 += __shfl_xor(p3, o);
        }
        if (lane == 0) {
            a_src[(long)n * 2 + 0] = p0; a_src[(long)n * 2 + 1] = p1;
            a_dst[(long)n * 2 + 0] = p2; a_dst[(long)n * 2 + 1] = p3;
        }
    }
}

// ------- launch 3: add block offsets -----------------------------------------
__global__ __launch_bounds__(1024) void scanC2_k(
    int* __restrict__ rowptr, const int* __restrict__ bsum, int NBLK, int N)
{
    __shared__ int bex_sh, tot_sh;
    int t = threadIdx.x;
    if (t < 64) {
        int lane = t;
        int v = (lane < NBLK) ? bsum[lane] : 0;
        int incl = v;
        #pragma unroll
        for (int o = 1; o < 64; o <<= 1) {
            int nb = __shfl_up(incl, o);
            if (lane >= o) incl += nb;
        }
        if (lane == (int)blockIdx.x) bex_sh = incl - v;
        if (lane == NBLK - 1) tot_sh = incl;
    }
    __syncthreads();
    int i = blockIdx.x * 1024 + t;
    if (i < N) rowptr[i] += bex_sh;
    if ((int)blockIdx.x == NBLK - 1 && t == 0) rowptr[N] = tot_sh;
}

// ------- launch 4: atomic-free scatter ---------------------------------------
__global__ void scatter_nc(const int* __restrict__ ei_s, const int* __restrict__ ei_d,
                           const int* __restrict__ rowptr, const int* __restrict__ pos,
                           int* __restrict__ csr_src, int* __restrict__ csr_eid,
                           int E, int Ep)
{
    int i = blockIdx.x * blockDim.x + threadIdx.x;
    if (i >= Ep) return;
    int s = (i < E) ? ei_s[i] : (i - E);
    int d = (i < E) ? ei_d[i] : (i - E);
    int at = rowptr[d] + pos[i];
    csr_src[at] = s;
    csr_eid[at] = (i < E) ? i : -1;
}

// ------- layer-1 aggregation in INPUT space ---------------------------------
__global__ __launch_bounds__(256) void agg1x(
    const int* __restrict__ rowptr, const int* __restrict__ csr_src,
    const float* __restrict__ a_s, const float* __restrict__ a_d,  // [N,2]
    const float* __restrict__ x, float* __restrict__ G, int N)
{
    int wave = threadIdx.x >> 6, lane = threadIdx.x & 63;
    int d = blockIdx.x * 4 + wave;
    if (d >= N) return;
    int row = rowptr[d], end = rowptr[d + 1];
    int h = lane >> 5, l5 = lane & 31;
    float adh = a_d[(long)d * 2 + h];
    float a0[4] = {0,0,0,0}, a1[4] = {0,0,0,0};
    float den = 0.f;
    for (int base = row; base < end; base += 32) {
        int cnt = min(32, end - base);
        int sreg = 0; float e = 0.f;
        if (l5 < cnt) {
            sreg = csr_src[base + l5];
            float v = a_s[(long)sreg * 2 + h] + adh;
            v = (v > 0.f) ? v : NEG * v;
            e = expf(v);
            den += e;
        }
        int jmax = (cnt + 1) >> 1;
        for (int j = 0; j < jmax; ++j) {
            int m = 2 * j + h;
            int s = __shfl(sreg, m);
            float w0 = __shfl(e, m);
            float w1 = __shfl(e, 32 | m);
            float4 v = *(const float4*)(x + (long)s * IN_F + l5 * 4);
            a0[0] = fmaf(w0, v.x, a0[0]); a0[1] = fmaf(w0, v.y, a0[1]);
            a0[2] = fmaf(w0, v.z, a0[2]); a0[3] = fmaf(w0, v.w, a0[3]);
            a1[0] = fmaf(w1, v.x, a1[0]); a1[1] = fmaf(w1, v.y, a1[1]);
            a1[2] = fmaf(w1, v.z, a1[2]); a1[3] = fmaf(w1, v.w, a1[3]);
        }
    }
    #pragma unroll
    for (int o = 16; o > 0; o >>= 1) den += __shfl_xor(den, o);
    #pragma unroll
    for (int p = 0; p < 4; ++p) {
        a0[p] += __shfl_xor(a0[p], 32);
        a1[p] += __shfl_xor(a1[p], 32);
    }
    float inv = 1.0f / (den + 1e-16f);
    float* acch = (h == 0) ? a0 : a1;
    float4 o4 = {acch[0] * inv, acch[1] * inv, acch[2] * inv, acch[3] * inv};
    *(float4*)(G + (long)d * F1 + h * 128 + l5 * 4) = o4;
}

// ------- layer-2 aggregation (bias fused into output) ------------------------
__global__ __launch_bounds__(256) void agg2_csr(
    const int* __restrict__ rowptr, const int* __restrict__ csr_src,
    const float* __restrict__ a_s, const float* __restrict__ a_d,  // [N]
    const float* __restrict__ xh2, const float* __restrict__ b2,
    float* __restrict__ out2b, int N)
{
    int wave = threadIdx.x >> 6, lane = threadIdx.x & 63;
    int d = blockIdx.x * 4 + wave;
    if (d >= N) return;
    int row = rowptr[d], end = rowptr[d + 1];
    float adv = a_d[d];
    int g = lane >> 4, q = lane & 15;
    float acc[4] = {0,0,0,0};
    float den = 0.f;
    for (int base = row; base < end; base += 64) {
        int cnt = min(64, end - base);
        float ev = 0.f; int sreg = 0;
        if (lane < cnt) {
            sreg = csr_src[base + lane];
            float v = a_s[sreg] + adv; v = (v > 0.f) ? v : NEG * v;
            ev = expf(v);
            den += ev;
        }
        int jmax = (cnt + 3) >> 2;
        for (int j = 0; j < jmax; ++j) {
            int m = 4 * j + g;
            int s = __shfl(sreg, m);
            float w = __shfl(ev, m);
            float4 v = *(const float4*)(xh2 + (long)s * F2 + q * 4);
            acc[0] = fmaf(w, v.x, acc[0]); acc[1] = fmaf(w, v.y, acc[1]);
            acc[2] = fmaf(w, v.z, acc[2]); acc[3] = fmaf(w, v.w, acc[3]);
        }
    }
    #pragma unroll
    for (int o = 32; o > 0; o >>= 1) den += __shfl_xor(den, o);
    #pragma unroll
    for (int p = 0; p < 4; ++p) {
        acc[p] += __shfl_xor(acc[p], 16);
        acc[p] += __shfl_xor(acc[p], 32);
    }
    if (g == 0) {
        float inv = 1.0f / (den + 1e-16f);
        float4 bb = *(const float4*)&b2[q * 4];
        float4 o4 = {acc[0] * inv + bb.x, acc[1] * inv + bb.y,
                     acc[2] * inv + bb.z, acc[3] * inv + bb.w};
        *(float4*)(out2b + (long)d * F2 + q * 4) = o4;
    }
}

// ------- decode via CSR ------------------------------------------------------
__global__ __launch_bounds__(256) void decode_csr(
    const int* __restrict__ rowptr, const int* __restrict__ csr_src,
    const int* __restrict__ csr_eid, const float* __restrict__ z2b,
    float* __restrict__ out, int N)
{
    int wave = threadIdx.x >> 6, lane = threadIdx.x & 63;
    int d = blockIdx.x * 4 + wave;
    if (d >= N) return;
    int row = rowptr[d], end = rowptr[d + 1];
    int g = lane >> 4, q = lane & 15;
    float4 vd = *(const float4*)(z2b + (long)d * F2 + q * 4);
    for (int base = row; base < end; base += 64) {
        int cnt = min(64, end - base);
        int sreg = 0, ereg = -1;
        if (lane < cnt) {
            sreg = csr_src[base + lane];
            ereg = csr_eid[base + lane];
        }
        int jmax = (cnt + 3) >> 2;
        for (int j = 0; j < jmax; ++j) {
            int m = 4 * j + g;
            int s = __shfl(sreg, m);
            int eid = __shfl(ereg, m);
            float4 vs = *(const float4*)(z2b + (long)s * F2 + q * 4);
            float p = vd.x * vs.x + vd.y * vs.y + vd.z * vs.z + vd.w * vs.w;
            #pragma unroll
            for (int o = 1; o < 16; o <<= 1) p += __shfl_xor(p, o);
            if (q == 0 && eid >= 0) out[eid] = p;
        }
    }
}

extern "C" void kernel_launch(void* const* d_in, const int* in_sizes, int n_in,
                              void* d_out, int out_size, void* d_ws, size_t ws_size,
                              hipStream_t stream) {
    const float* x   = (const float*)d_in[0];
    const int*   ei  = (const int*)d_in[1];
    const float* W1  = (const float*)d_in[2];
    const float* as1 = (const float*)d_in[3];
    const float* ad1 = (const float*)d_in[4];
    const float* b1  = (const float*)d_in[5];
    const float* W2  = (const float*)d_in[6];
    const float* as2 = (const float*)d_in[7];
    const float* ad2 = (const float*)d_in[8];
    const float* b2  = (const float*)d_in[9];

    int N  = in_sizes[0] / IN_F;   // 50000
    int E  = in_sizes[1] / 2;      // 600000
    int Ep = E + N;
    const int* ei_src = ei;
    const int* ei_dst = ei + E;

    float* ws = (float*)d_ws;
    size_t off = 0;
    auto alloc = [&](size_t n) { float* p = ws + off; off += (n + 63) & ~(size_t)63; return p; };

    float* G      = alloc((size_t)N * F1);
    float* z1     = alloc((size_t)N * F1);
    float* xh2    = alloc((size_t)N * F2);
    float* out2b  = alloc((size_t)N * F2);
    float* a_src1 = alloc((size_t)N * H1);
    float* a_dst1 = alloc((size_t)N * H1);
    float* a_src2 = alloc(N);
    float* a_dst2 = alloc(N);
    float* UV4    = alloc(IN_F * 4);
    int* rowptr   = (int*)alloc(N + 64);
    int* csr_src  = (int*)alloc(Ep);
    int* csr_eid  = (int*)alloc(Ep);
    int* pos      = (int*)alloc(Ep);
    int* bsum     = (int*)alloc(64);
    int* deg      = (int*)alloc(N);
    hipMemsetAsync(deg, 0, (size_t)N * sizeof(int), stream);

    int NBLK = (N + 1023) / 1024;       // 49
    int NBH  = (Ep + 255) / 256;        // 2540 hist blocks
    int NBA  = (N + 15) / 16;           // 3125 att blocks

    hist_uv_k<<<NBH + 1, 256, 0, stream>>>(ei_dst, deg, pos, E, Ep, NBH,
                                           W1, as1, ad1, UV4);
    scanA_att_k<<<NBLK + NBA, 1024, 0, stream>>>(deg, rowptr, bsum, N, NBLK,
                                                 x, UV4, a_src1, a_dst1);
    scanC2_k<<<NBLK, 1024, 0, stream>>>(rowptr, bsum, NBLK, N);
    scatter_nc<<<NBH, 256, 0, stream>>>(ei_src, ei_dst, rowptr, pos,
                                        csr_src, csr_eid, E, Ep);

    // layer 1: aggregate x in input space, then per-head GEMM (W-resident)
    agg1x<<<(N + 3) / 4, 256, 0, stream>>>(rowptr, csr_src, a_src1, a_dst1, x, G, N);
    int mt1 = (N + 127) / 128;
    gemm_wlds<IN_F, 128, 128, 8, 8, F1, F1, F1, false, false, true>
        <<<dim3(mt1, 2), 256, 0, stream>>>(
        G, nullptr, W1, z1, nullptr, nullptr, nullptr, nullptr, N);

    // layer 2
    gemm_wlds<F1, 128, 64, 4, 8, F1, F2, F2, true, true, false>
        <<<dim3(mt1, 1), 256, 0, stream>>>(
        z1, b1, W2, xh2, as2, ad2, a_src2, a_dst2, N);
    agg2_csr<<<(N + 3) / 4, 256, 0, stream>>>(rowptr, csr_src, a_src2, a_dst2, xh2, b2, out2b, N);

    // decode via CSR
    decode_csr<<<(N + 3) / 4, 256, 0, stream>>>(rowptr, csr_src, csr_eid, out2b,
                                                (float*)d_out, N);
}

// Round 13
// 338.690 us; speedup vs baseline: 1.1282x; 1.0214x over previous
//
#include <hip/hip_runtime.h>
#include <math.h>

#define IN_F 128
#define F1 256   // H1*C1
#define H1 2
#define F2 64
#define NEG 0.2f

// ---------------- tiled fp32 GEMM (round-9 best: split-col, SK=32) ----------
template<int KTOT, int TM, int TN, int RM, int RN, int LDA, int LDW, int LDC,
         bool RELU, bool ATT_EP, bool HEADOFF>
__global__ __launch_bounds__(256) void gemm_tiled(
    const float* __restrict__ A, const float* __restrict__ bias,
    const float* __restrict__ W, float* __restrict__ C,
    const float* __restrict__ att_s, const float* __restrict__ att_d,
    float* __restrict__ a_src, float* __restrict__ a_dst, int M)
{
    constexpr int NX = TN / RN;
    constexpr int NY = 256 / NX;
    static_assert(NY * RM == TM, "tile mismatch");
    static_assert(RN == 8, "split-col mapping assumes RN==8");
    __shared__ float As[32][TM];
    __shared__ float Ws[32][TN];
    int t = threadIdx.x;
    int tx = t % NX, ty = t / NX;
    int m0 = blockIdx.x * TM;
    int n0 = blockIdx.y * TN;
    long aoff = HEADOFF ? (long)blockIdx.y * KTOT : 0;
    float acc[RM][RN];
    #pragma unroll
    for (int i = 0; i < RM; ++i)
        #pragma unroll
        for (int j = 0; j < RN; ++j) acc[i][j] = 0.f;

    constexpr int PARTS = 256 / TM;
    constexpr int F4PT = 8 / PARTS;
    int ar = t % TM, apart = t / TM;
    int arow = m0 + ar; if (arow >= M) arow = M - 1;
    constexpr int WTPK = TN / 4;
    constexpr int WKP = 256 / WTPK;
    int wk0 = t / WTPK, wc = t % WTPK;

    for (int kc = 0; kc < KTOT; kc += 32) {
        const float* ap = A + (long)arow * LDA + aoff + kc + apart * (F4PT * 4);
        #pragma unroll
        for (int p = 0; p < F4PT; ++p) {
            int kk = apart * (F4PT * 4) + p * 4;
            float4 v = *(const float4*)(ap + p * 4);
            if (RELU) {
                float4 bb = *(const float4*)&bias[kc + kk];
                v.x = fmaxf(v.x + bb.x, 0.f);
                v.y = fmaxf(v.y + bb.y, 0.f);
                v.z = fmaxf(v.z + bb.z, 0.f);
                v.w = fmaxf(v.w + bb.w, 0.f);
            }
            As[kk + 0][ar] = v.x;
            As[kk + 1][ar] = v.y;
            As[kk + 2][ar] = v.z;
            As[kk + 3][ar] = v.w;
        }
        #pragma unroll
        for (int p = 0; p < 32 / WKP; ++p) {
            int k = wk0 + p * WKP;
            *(float4*)&Ws[k][wc * 4] =
                *(const float4*)&W[(long)(kc + k) * LDW + n0 + wc * 4];
        }
        __syncthreads();
        #pragma unroll 4
        for (int k = 0; k < 32; ++k) {
            float av[RM], wv[RN];
            #pragma unroll
            for (int i4 = 0; i4 < RM / 4; ++i4) {
                float4 v = *(const float4*)&As[k][ty * RM + i4 * 4];
                av[i4 * 4 + 0] = v.x; av[i4 * 4 + 1] = v.y;
                av[i4 * 4 + 2] = v.z; av[i4 * 4 + 3] = v.w;
            }
            {
                float4 v = *(const float4*)&Ws[k][tx * 4];
                wv[0] = v.x; wv[1] = v.y; wv[2] = v.z; wv[3] = v.w;
                float4 u = *(const float4*)&Ws[k][TN / 2 + tx * 4];
                wv[4] = u.x; wv[5] = u.y; wv[6] = u.z; wv[7] = u.w;
            }
            #pragma unroll
            for (int i = 0; i < RM; ++i)
                #pragma unroll
                for (int j = 0; j < RN; ++j)
                    acc[i][j] = fmaf(av[i], wv[j], acc[i][j]);
        }
        __syncthreads();
    }
    #pragma unroll
    for (int i = 0; i < RM; ++i) {
        int row = m0 + ty * RM + i;
        if (row < M) {
            float4 o0 = {acc[i][0], acc[i][1], acc[i][2], acc[i][3]};
            float4 o1 = {acc[i][4], acc[i][5], acc[i][6], acc[i][7]};
            *(float4*)&C[(long)row * LDC + n0 + tx * 4] = o0;
            *(float4*)&C[(long)row * LDC + n0 + TN / 2 + tx * 4] = o1;
        }
    }
    if (ATT_EP) {
        float asr[RN], adr[RN];
        #pragma unroll
        for (int j = 0; j < RN; ++j) {
            int col = (j < 4) ? (tx * 4 + j) : (TN / 2 + tx * 4 + j - 4);
            asr[j] = att_s[col];
            adr[j] = att_d[col];
        }
        #pragma unroll
        for (int i = 0; i < RM; ++i) {
            float ps = 0.f, pd = 0.f;
            #pragma unroll
            for (int j = 0; j < RN; ++j) {
                ps = fmaf(acc[i][j], asr[j], ps);
                pd = fmaf(acc[i][j], adr[j], pd);
            }
            #pragma unroll
            for (int o = 1; o < NX; o <<= 1) {
                ps += __shfl_xor(ps, o);
                pd += __shfl_xor(pd, o);
            }
            int row = m0 + ty * RM + i;
            if (tx == 0 && row < M) { a_src[row] = ps; a_dst[row] = pd; }
        }
    }
}

// ------- launch 1: histogram w/ position recording + UV precompute -----------
__global__ __launch_bounds__(256) void hist_uv_k(
    const int* __restrict__ ei_d, int* __restrict__ deg, int* __restrict__ pos,
    int E, int Ep, int NBH,
    const float* __restrict__ W1, const float* __restrict__ as1,
    const float* __restrict__ ad1, float* __restrict__ UV4)
{
    if ((int)blockIdx.x < NBH) {
        int i = blockIdx.x * 256 + threadIdx.x;
        if (i >= Ep) return;
        int d = (i < E) ? ei_d[i] : (i - E);
        pos[i] = atomicAdd(&deg[d], 1);
    } else {
        int t = threadIdx.x;
        int k = t >> 1, h = t & 1;
        const float* wrow = W1 + (long)k * F1 + h * 128;
        const float* sa = as1 + h * 128;
        const float* da = ad1 + h * 128;
        float u = 0.f, v = 0.f;
        for (int c = 0; c < 128; ++c) {
            float w = wrow[c];
            u = fmaf(w, sa[c], u);
            v = fmaf(w, da[c], v);
        }
        UV4[k * 4 + h] = u;
        UV4[k * 4 + 2 + h] = v;
    }
}

// ------- launch 2: per-block local scan -> rloc (blocks [0,NBLK)) + att1v ----
__global__ __launch_bounds__(1024) void scanA_att_k(
    const int* __restrict__ deg, int* __restrict__ rloc, int* __restrict__ bsum,
    int N, int NBLK,
    const float* __restrict__ x, const float* __restrict__ UV4,
    float* __restrict__ a_src, float* __restrict__ a_dst)
{
    if ((int)blockIdx.x < NBLK) {
        __shared__ int wsum[16];
        int t = threadIdx.x, lane = t & 63, w = t >> 6;
        int i = blockIdx.x * 1024 + t;
        int v = (i < N) ? deg[i] : 0;
        int incl = v;
        #pragma unroll
        for (int o = 1; o < 64; o <<= 1) {
            int nb = __shfl_up(incl, o);
            if (lane >= o) incl += nb;
        }
        if (lane == 63) wsum[w] = incl;
        __syncthreads();
        if (w == 0 && lane < 16) {
            int s = wsum[lane];
            #pragma unroll
            for (int o = 1; o < 16; o <<= 1) {
                int nb = __shfl_up(s, o);
                if (lane >= o) s += nb;
            }
            wsum[lane] = s;
        }
        __syncthreads();
        int woff = (w == 0) ? 0 : wsum[w - 1];
        if (i < N) rloc[i] = woff + incl - v;
        if (t == 1023) bsum[blockIdx.x] = woff + incl;
    } else {
        int wave = threadIdx.x >> 6, lane = threadIdx.x & 63;
        int n = ((int)blockIdx.x - NBLK) * 16 + wave;
        if (n >= N) return;
        float2 xv = ((const float2*)(x + (long)n * IN_F))[lane];
        float4 u0 = ((const float4*)UV4)[2 * lane];
        float4 u1 = ((const float4*)UV4)[2 * lane + 1];
        float p0 = xv.x * u0.x + xv.y * u1.x;
        float p1 = xv.x * u0.y + xv.y * u1.y;
        float p2 = xv.x * u0.z + xv.y * u1.z;
        float p3 = xv.x * u0.w + xv.y * u1.w;
        #pragma unroll
        for (int o = 32; o > 0; o >>= 1) {
            p0 += __shfl_xor(p0, o); p1 += __shfl_xor(p1, o);
            p2 += __shfl_xor(p2, o); p3 += __shfl_xor(p3, o);
        }
        if (lane == 0) {
            a_src[(long)n * 2 + 0] = p0; a_src[(long)n * 2 + 1] = p1;
            a_dst[(long)n * 2 + 0] = p2; a_dst[(long)n * 2 + 1] = p3;
        }
    }
}

// ------- launch 3 (fused): rowptr fixup + atomic-free scatter ----------------
// Every block re-derives the 64-entry bex scan inline (cheap) so fixup and
// scatter don't race: both read only rloc/bsum/pos, never in-flight rowptr.
__global__ __launch_bounds__(1024) void scat_fix_k(
    const int* __restrict__ ei_s, const int* __restrict__ ei_d,
    const int* __restrict__ rloc, const int* __restrict__ bsum,
    const int* __restrict__ pos, int* __restrict__ rowptr,
    int* __restrict__ csr_src, int* __restrict__ csr_eid,
    int E, int Ep, int N, int NBLK)
{
    __shared__ int bexs[64];
    __shared__ int tot_sh;
    int t = threadIdx.x;
    if (t < 64) {
        int v = (t < NBLK) ? bsum[t] : 0;
        int incl = v;
        #pragma unroll
        for (int o = 1; o < 64; o <<= 1) {
            int nb = __shfl_up(incl, o);
            if (t >= o) incl += nb;
        }
        bexs[t] = incl - v;
        if (t == NBLK - 1) tot_sh = incl;
    }
    __syncthreads();
    if ((int)blockIdx.x < NBLK) {
        int i = blockIdx.x * 1024 + t;
        if (i < N) rowptr[i] = rloc[i] + bexs[blockIdx.x];
        if ((int)blockIdx.x == NBLK - 1 && t == 0) rowptr[N] = tot_sh;
    } else {
        int i = ((int)blockIdx.x - NBLK) * 1024 + t;
        if (i >= Ep) return;
        int s = (i < E) ? ei_s[i] : (i - E);
        int d = (i < E) ? ei_d[i] : (i - E);
        int at = rloc[d] + bexs[d >> 10] + pos[i];
        csr_src[at] = s;
        csr_eid[at] = (i < E) ? i : -1;
    }
}

// ------- layer-1 aggregation in INPUT space ---------------------------------
__global__ __launch_bounds__(256) void agg1x(
    const int* __restrict__ rowptr, const int* __restrict__ csr_src,
    const float* __restrict__ a_s, const float* __restrict__ a_d,  // [N,2]
    const float* __restrict__ x, float* __restrict__ G, int N)
{
    int wave = threadIdx.x >> 6, lane = threadIdx.x & 63;
    int d = blockIdx.x * 4 + wave;
    if (d >= N) return;
    int row = rowptr[d], end = rowptr[d + 1];
    int h = lane >> 5, l5 = lane & 31;
    float adh = a_d[(long)d * 2 + h];
    float a0[4] = {0,0,0,0}, a1[4] = {0,0,0,0};
    float den = 0.f;
    for (int base = row; base < end; base += 32) {
        int cnt = min(32, end - base);
        int sreg = 0; float e = 0.f;
        if (l5 < cnt) {
            sreg = csr_src[base + l5];
            float v = a_s[(long)sreg * 2 + h] + adh;
            v = (v > 0.f) ? v : NEG * v;
            e = expf(v);
            den += e;
        }
        int jmax = (cnt + 1) >> 1;
        for (int j = 0; j < jmax; ++j) {
            int m = 2 * j + h;
            int s = __shfl(sreg, m);
            float w0 = __shfl(e, m);
            float w1 = __shfl(e, 32 | m);
            float4 v = *(const float4*)(x + (long)s * IN_F + l5 * 4);
            a0[0] = fmaf(w0, v.x, a0[0]); a0[1] = fmaf(w0, v.y, a0[1]);
            a0[2] = fmaf(w0, v.z, a0[2]); a0[3] = fmaf(w0, v.w, a0[3]);
            a1[0] = fmaf(w1, v.x, a1[0]); a1[1] = fmaf(w1, v.y, a1[1]);
            a1[2] = fmaf(w1, v.z, a1[2]); a1[3] = fmaf(w1, v.w, a1[3]);
        }
    }
    #pragma unroll
    for (int o = 16; o > 0; o >>= 1) den += __shfl_xor(den, o);
    #pragma unroll
    for (int p = 0; p < 4; ++p) {
        a0[p] += __shfl_xor(a0[p], 32);
        a1[p] += __shfl_xor(a1[p], 32);
    }
    float inv = 1.0f / (den + 1e-16f);
    float* acch = (h == 0) ? a0 : a1;
    float4 o4 = {acch[0] * inv, acch[1] * inv, acch[2] * inv, acch[3] * inv};
    *(float4*)(G + (long)d * F1 + h * 128 + l5 * 4) = o4;
}

// ------- layer-2 aggregation (bias fused into output) ------------------------
__global__ __launch_bounds__(256) void agg2_csr(
    const int* __restrict__ rowptr, const int* __restrict__ csr_src,
    const float* __restrict__ a_s, const float* __restrict__ a_d,  // [N]
    const float* __restrict__ xh2, const float* __restrict__ b2,
    float* __restrict__ out2b, int N)
{
    int wave = threadIdx.x >> 6, lane = threadIdx.x & 63;
    int d = blockIdx.x * 4 + wave;
    if (d >= N) return;
    int row = rowptr[d], end = rowptr[d + 1];
    float adv = a_d[d];
    int g = lane >> 4, q = lane & 15;
    float acc[4] = {0,0,0,0};
    float den = 0.f;
    for (int base = row; base < end; base += 64) {
        int cnt = min(64, end - base);
        float ev = 0.f; int sreg = 0;
        if (lane < cnt) {
            sreg = csr_src[base + lane];
            float v = a_s[sreg] + adv; v = (v > 0.f) ? v : NEG * v;
            ev = expf(v);
            den += ev;
        }
        int jmax = (cnt + 3) >> 2;
        for (int j = 0; j < jmax; ++j) {
            int m = 4 * j + g;
            int s = __shfl(sreg, m);
            float w = __shfl(ev, m);
            float4 v = *(const float4*)(xh2 + (long)s * F2 + q * 4);
            acc[0] = fmaf(w, v.x, acc[0]); acc[1] = fmaf(w, v.y, acc[1]);
            acc[2] = fmaf(w, v.z, acc[2]); acc[3] = fmaf(w, v.w, acc[3]);
        }
    }
    #pragma unroll
    for (int o = 32; o > 0; o >>= 1) den += __shfl_xor(den, o);
    #pragma unroll
    for (int p = 0; p < 4; ++p) {
        acc[p] += __shfl_xor(acc[p], 16);
        acc[p] += __shfl_xor(acc[p], 32);
    }
    if (g == 0) {
        float inv = 1.0f / (den + 1e-16f);
        float4 bb = *(const float4*)&b2[q * 4];
        float4 o4 = {acc[0] * inv + bb.x, acc[1] * inv + bb.y,
                     acc[2] * inv + bb.z, acc[3] * inv + bb.w};
        *(float4*)(out2b + (long)d * F2 + q * 4) = o4;
    }
}

// ------- decode via CSR ------------------------------------------------------
__global__ __launch_bounds__(256) void decode_csr(
    const int* __restrict__ rowptr, const int* __restrict__ csr_src,
    const int* __restrict__ csr_eid, const float* __restrict__ z2b,
    float* __restrict__ out, int N)
{
    int wave = threadIdx.x >> 6, lane = threadIdx.x & 63;
    int d = blockIdx.x * 4 + wave;
    if (d >= N) return;
    int row = rowptr[d], end = rowptr[d + 1];
    int g = lane >> 4, q = lane & 15;
    float4 vd = *(const float4*)(z2b + (long)d * F2 + q * 4);
    for (int base = row; base < end; base += 64) {
        int cnt = min(64, end - base);
        int sreg = 0, ereg = -1;
        if (lane < cnt) {
            sreg = csr_src[base + lane];
            ereg = csr_eid[base + lane];
        }
        int jmax = (cnt + 3) >> 2;
        for (int j = 0; j < jmax; ++j) {
            int m = 4 * j + g;
            int s = __shfl(sreg, m);
            int eid = __shfl(ereg, m);
            float4 vs = *(const float4*)(z2b + (long)s * F2 + q * 4);
            float p = vd.x * vs.x + vd.y * vs.y + vd.z * vs.z + vd.w * vs.w;
            #pragma unroll
            for (int o = 1; o < 16; o <<= 1) p += __shfl_xor(p, o);
            if (q == 0 && eid >= 0) out[eid] = p;
        }
    }
}

extern "C" void kernel_launch(void* const* d_in, const int* in_sizes, int n_in,
                              void* d_out, int out_size, void* d_ws, size_t ws_size,
                              hipStream_t stream) {
    const float* x   = (const float*)d_in[0];
    const int*   ei  = (const int*)d_in[1];
    const float* W1  = (const float*)d_in[2];
    const float* as1 = (const float*)d_in[3];
    const float* ad1 = (const float*)d_in[4];
    const float* b1  = (const float*)d_in[5];
    const float* W2  = (const float*)d_in[6];
    const float* as2 = (const float*)d_in[7];
    const float* ad2 = (const float*)d_in[8];
    const float* b2  = (const float*)d_in[9];

    int N  = in_sizes[0] / IN_F;   // 50000
    int E  = in_sizes[1] / 2;      // 600000
    int Ep = E + N;
    const int* ei_src = ei;
    const int* ei_dst = ei + E;

    float* ws = (float*)d_ws;
    size_t off = 0;
    auto alloc = [&](size_t n) { float* p = ws + off; off += (n + 63) & ~(size_t)63; return p; };

    float* G      = alloc((size_t)N * F1);
    float* z1     = alloc((size_t)N * F1);
    float* xh2    = alloc((size_t)N * F2);
    float* out2b  = alloc((size_t)N * F2);
    float* a_src1 = alloc((size_t)N * H1);
    float* a_dst1 = alloc((size_t)N * H1);
    float* a_src2 = alloc(N);
    float* a_dst2 = alloc(N);
    float* UV4    = alloc(IN_F * 4);
    int* rowptr   = (int*)alloc(N + 64);
    int* rloc     = (int*)alloc(N + 64);
    int* csr_src  = (int*)alloc(Ep);
    int* csr_eid  = (int*)alloc(Ep);
    int* pos      = (int*)alloc(Ep);
    int* bsum     = (int*)alloc(64);
    int* deg      = (int*)alloc(N);
    hipMemsetAsync(deg, 0, (size_t)N * sizeof(int), stream);

    int NBLK = (N + 1023) / 1024;       // 49
    int NBH  = (Ep + 255) / 256;        // hist blocks (256 thr)
    int NBS  = (Ep + 1023) / 1024;      // scatter blocks (1024 thr)
    int NBA  = (N + 15) / 16;           // att blocks

    hist_uv_k<<<NBH + 1, 256, 0, stream>>>(ei_dst, deg, pos, E, Ep, NBH,
                                           W1, as1, ad1, UV4);
    scanA_att_k<<<NBLK + NBA, 1024, 0, stream>>>(deg, rloc, bsum, N, NBLK,
                                                 x, UV4, a_src1, a_dst1);
    scat_fix_k<<<NBLK + NBS, 1024, 0, stream>>>(ei_src, ei_dst, rloc, bsum, pos,
                                                rowptr, csr_src, csr_eid,
                                                E, Ep, N, NBLK);

    // layer 1: aggregate x in input space, then per-head GEMM
    agg1x<<<(N + 3) / 4, 256, 0, stream>>>(rowptr, csr_src, a_src1, a_dst1, x, G, N);
    int mt1 = (N + 127) / 128;
    gemm_tiled<IN_F, 128, 128, 8, 8, F1, F1, F1, false, false, true>
        <<<dim3(mt1, 2), 256, 0, stream>>>(
        G, nullptr, W1, z1, nullptr, nullptr, nullptr, nullptr, N);

    // layer 2
    gemm_tiled<F1, 128, 64, 4, 8, F1, F2, F2, true, true, false>
        <<<dim3(mt1, 1), 256, 0, stream>>>(
        z1, b1, W2, xh2, as2, ad2, a_src2, a_dst2, N);
    agg2_csr<<<(N + 3) / 4, 256, 0, stream>>>(rowptr, csr_src, a_src2, a_dst2, xh2, b2, out2b, N);

    // decode via CSR
    decode_csr<<<(N + 3) / 4, 256, 0, stream>>>(rowptr, csr_src, csr_eid, out2b,
                                                (float*)d_out, N);
}